// Round 1
// baseline (380.864 us; speedup 1.0000x reference)
//
#include <hip/hip_runtime.h>

// DenseGINEConv fused kernel for MI355X (gfx950).
// B=4, N=512, F=64, H=128, fp32. Memory-bound on edge_attr (256 MiB read-once).
// One block per output row (b,j): 256 threads = 16 f-groups(float4) x 16 i-partials.

namespace {

constexpr int Bc = 4;
constexpr int Nc = 512;
constexpr int Fc = 64;
constexpr int Hc = 128;
constexpr float NEG = 0.01f;

__device__ __forceinline__ float lrelu(float z) {
  return z > 0.f ? z : z * NEG;
}

__global__ __launch_bounds__(256) void gine_fused(
    const float* __restrict__ x,    // (B,N,F)
    const float* __restrict__ adj,  // (B,N,N)
    const float* __restrict__ ea,   // (B,N,N,F)
    const int* __restrict__ mask,   // (B,N) int32 0/1
    const float* __restrict__ W1,   // (F,H)
    const float* __restrict__ b1,   // (H)
    const float* __restrict__ W2,   // (H,F)
    const float* __restrict__ b2,   // (F)
    float* __restrict__ out)        // (B,N,F)
{
  const int blk = blockIdx.x;
  const int b = blk >> 9;          // blk / N
  const int j = blk & (Nc - 1);    // blk % N
  const int tid = threadIdx.x;
  const int f4 = tid & 15;         // float4 group over F (f = f4*4)
  const int ip = tid >> 4;         // 0..15 partial over source index i

  __shared__ float s_adj[Nc];      // adj[b, :, j]
  __shared__ float4 s_part[256];   // partial sums, layout [ip][f4]
  __shared__ float s_out[Fc];      // aggregated row (pre-MLP)
  __shared__ float s_hid[Hc];      // hidden activations

  // ---- stage adj column j (strided; tiny, 2 KiB) ----
  const float* adjb = adj + b * Nc * Nc;
  s_adj[tid]       = adjb[tid * Nc + j];
  s_adj[tid + 256] = adjb[(tid + 256) * Nc + j];
  __syncthreads();

  // ---- main aggregation: acc[f] = sum_i lrelu(adj[b,i,j]*(x[b,i,f]+ea[b,i,j,f])) ----
  const float4* xb  = reinterpret_cast<const float4*>(x + b * Nc * Fc);
  const float4* eab = reinterpret_cast<const float4*>(ea) +
                      ((b * Nc) * Nc + j) * (Fc / 4);

  float4 acc = make_float4(0.f, 0.f, 0.f, 0.f);
  #pragma unroll 4
  for (int i = ip; i < Nc; i += 16) {
    const float a = s_adj[i];
    const float4 xv = xb[i * (Fc / 4) + f4];          // L2-resident re-read
    const float4 ev = eab[i * (Nc * Fc / 4) + f4];    // streaming 256 MiB
    acc.x += lrelu(a * (xv.x + ev.x));
    acc.y += lrelu(a * (xv.y + ev.y));
    acc.z += lrelu(a * (xv.z + ev.z));
    acc.w += lrelu(a * (xv.w + ev.w));
  }

  // ---- reduce 16 i-partials (layout index = ip*16 + f4 == tid) ----
  s_part[tid] = acc;
  __syncthreads();
  #pragma unroll
  for (int s = 128; s >= 16; s >>= 1) {
    if (tid < s) {
      float4 p = s_part[tid];
      const float4 q = s_part[tid + s];
      p.x += q.x; p.y += q.y; p.z += q.z; p.w += q.w;
      s_part[tid] = p;
    }
    __syncthreads();
  }

  // ---- add self-loop x[b,j,:] (EPS=0) and stash row in LDS ----
  if (tid < 16) {
    float4 r = s_part[tid];
    const float4 xj = xb[j * (Fc / 4) + tid];
    r.x += xj.x; r.y += xj.y; r.z += xj.z; r.w += xj.w;
    reinterpret_cast<float4*>(s_out)[tid] = r;
  }
  __syncthreads();

  // ---- fused MLP: hid = lrelu(row @ W1 + b1) ----
  if (tid < Hc) {
    float h = b1[tid];
    #pragma unroll
    for (int f = 0; f < Fc; ++f)
      h = fmaf(s_out[f], W1[f * Hc + tid], h);   // coalesced across tid; L2-resident
    s_hid[tid] = lrelu(h);
  }
  __syncthreads();

  // ---- o = hid @ W2 + b2, masked write ----
  if (tid < Fc) {
    float o = b2[tid];
    #pragma unroll
    for (int h = 0; h < Hc; ++h)
      o = fmaf(s_hid[h], W2[h * Fc + tid], o);
    const int row = b * Nc + j;
    out[row * Fc + tid] = (mask[row] != 0) ? o : 0.f;
  }
}

} // namespace

extern "C" void kernel_launch(void* const* d_in, const int* in_sizes, int n_in,
                              void* d_out, int out_size, void* d_ws, size_t ws_size,
                              hipStream_t stream) {
  const float* x    = (const float*)d_in[0];
  const float* adj  = (const float*)d_in[1];
  const float* ea   = (const float*)d_in[2];
  const int*   mask = (const int*)d_in[3];
  const float* W1   = (const float*)d_in[4];
  const float* b1   = (const float*)d_in[5];
  const float* W2   = (const float*)d_in[6];
  const float* b2   = (const float*)d_in[7];
  float* out = (float*)d_out;

  gine_fused<<<dim3(Bc * Nc), dim3(256), 0, stream>>>(
      x, adj, ea, mask, W1, b1, W2, b2, out);
}

// Round 2
// 377.560 us; speedup vs baseline: 1.0088x; 1.0088x over previous
//
#include <hip/hip_runtime.h>

// DenseGINEConv fused kernel for MI355X (gfx950).
// B=4, N=512, F=64, H=128, fp32. Memory-bound on edge_attr (256 MiB read-once).
// Round 2: j-tile TJ=4 per block so each wave's ea load is 1 KiB contiguous
// (was 256 B at 128 KiB stride -> poor DRAM burst efficiency).
// Block = (b, j0..j0+3): 512 threads = 8 ip x 4 jl x 16 f4.

namespace {

constexpr int Bc = 4;
constexpr int Nc = 512;
constexpr int Fc = 64;
constexpr int Hc = 128;
constexpr int TJ = 4;          // j-tile per block
constexpr int TH = 512;        // threads per block
constexpr float NEG = 0.01f;

__device__ __forceinline__ float lrelu(float z) {
  return z > 0.f ? z : z * NEG;
}

__global__ __launch_bounds__(TH, 4) void gine_fused(
    const float* __restrict__ x,    // (B,N,F)
    const float* __restrict__ adj,  // (B,N,N)
    const float* __restrict__ ea,   // (B,N,N,F)
    const int* __restrict__ mask,   // (B,N) int32 0/1
    const float* __restrict__ W1,   // (F,H)
    const float* __restrict__ b1,   // (H)
    const float* __restrict__ W2,   // (H,F)
    const float* __restrict__ b2,   // (F)
    float* __restrict__ out)        // (B,N,F)
{
  const int blk = blockIdx.x;            // 0 .. B*N/TJ-1 = 511
  const int b   = blk >> 7;              // blk / (N/TJ = 128)
  const int j0  = (blk & 127) * TJ;
  const int tid = threadIdx.x;
  const int f4  = tid & 15;              // float4 group over F
  const int jl  = (tid >> 4) & 3;        // which j within tile
  const int ip  = tid >> 6;              // 0..7 partial over source i

  __shared__ float4 s_adj4[Nc];          // [i] = adj[b,i,j0..j0+3]
  __shared__ float4 s_part[TH];
  __shared__ float  s_out[TJ][Fc];
  __shared__ float  s_hid[TJ][Hc];

  // ---- stage adj columns j0..j0+3 (8 KiB; 16B/lane strided, L2-shared across tiles) ----
  const float* adjb = adj + (size_t)b * Nc * Nc;
  s_adj4[tid] = *reinterpret_cast<const float4*>(adjb + (size_t)tid * Nc + j0);
  __syncthreads();

  // ---- aggregation: acc[jl][f] = sum_i lrelu(adj[b,i,j0+jl]*(x[b,i,f]+ea[b,i,j0+jl,f])) ----
  const float4* xb4 = reinterpret_cast<const float4*>(x + (size_t)b * Nc * Fc);
  const float4* eap = reinterpret_cast<const float4*>(ea)
                    + ((size_t)b * Nc * Nc + (j0 + jl)) * (Fc / 4) + f4;
  // per-i stride in float4 units:
  constexpr int ISTRIDE = Nc * Fc / 4;   // 8192

  float4 acc = make_float4(0.f, 0.f, 0.f, 0.f);
  #pragma unroll 4
  for (int i = ip; i < Nc; i += 8) {
    const float a   = reinterpret_cast<const float*>(&s_adj4[i])[jl]; // broadcast x4
    const float4 xv = xb4[i * (Fc / 4) + f4];                          // L1/L2 hit
    const float4 ev = eap[(size_t)i * ISTRIDE];                        // 1 KiB/wave contiguous
    acc.x += lrelu(a * (xv.x + ev.x));
    acc.y += lrelu(a * (xv.y + ev.y));
    acc.z += lrelu(a * (xv.z + ev.z));
    acc.w += lrelu(a * (xv.w + ev.w));
  }

  // ---- reduce 8 ip-partials; partials for (jl,f4) live at stride 64 ----
  s_part[tid] = acc;
  __syncthreads();
  #pragma unroll
  for (int s = 256; s >= 64; s >>= 1) {
    if (tid < s) {
      float4 p = s_part[tid];
      const float4 q = s_part[tid + s];
      p.x += q.x; p.y += q.y; p.z += q.z; p.w += q.w;
      s_part[tid] = p;
    }
    __syncthreads();
  }

  // ---- add self-loop x[b,j,:] (EPS=0), stash 4 rows ----
  if (tid < 64) {
    const int row = tid >> 4;            // 0..3
    const int fg  = tid & 15;
    float4 r = s_part[tid];
    const float4 xj = xb4[(j0 + row) * (Fc / 4) + fg];
    r.x += xj.x; r.y += xj.y; r.z += xj.z; r.w += xj.w;
    reinterpret_cast<float4*>(&s_out[row][0])[fg] = r;
  }
  __syncthreads();

  // ---- MLP stage 1: hid[row][h] = lrelu(row @ W1 + b1); all 512 threads ----
  {
    const int row = tid >> 7;            // 0..3
    const int h   = tid & 127;
    float hv = b1[h];
    #pragma unroll 8
    for (int f = 0; f < Fc; ++f)
      hv = fmaf(s_out[row][f], W1[f * Hc + h], hv);  // coalesced over h, L1-resident
    s_hid[row][h] = lrelu(hv);
  }
  __syncthreads();

  // ---- MLP stage 2: o = hid @ W2 + b2, masked write (256 threads) ----
  if (tid < TJ * Fc) {
    const int row = tid >> 6;            // 0..3
    const int f   = tid & 63;
    float o = b2[f];
    #pragma unroll 8
    for (int h = 0; h < Hc; ++h)
      o = fmaf(s_hid[row][h], W2[h * Fc + f], o);
    const int rowg = b * Nc + j0 + row;
    out[rowg * Fc + f] = (mask[rowg] != 0) ? o : 0.f;
  }
}

} // namespace

extern "C" void kernel_launch(void* const* d_in, const int* in_sizes, int n_in,
                              void* d_out, int out_size, void* d_ws, size_t ws_size,
                              hipStream_t stream) {
  const float* x    = (const float*)d_in[0];
  const float* adj  = (const float*)d_in[1];
  const float* ea   = (const float*)d_in[2];
  const int*   mask = (const int*)d_in[3];
  const float* W1   = (const float*)d_in[4];
  const float* b1   = (const float*)d_in[5];
  const float* W2   = (const float*)d_in[6];
  const float* b2   = (const float*)d_in[7];
  float* out = (float*)d_out;

  gine_fused<<<dim3(Bc * Nc / TJ), dim3(TH), 0, stream>>>(
      x, adj, ea, mask, W1, b1, W2, b2, out);
}